// Round 8
// baseline (111.154 us; speedup 1.0000x reference)
//
#include <hip/hip_runtime.h>

// CRF forward (log-partition) — B=1024, T=512, K=64. One wave per batch.
// Exp-domain recurrence: u <- (E·u) * F, F = exp(emit - 4.5) computed
// off-chain from chunk-prefetched emissions; C accumulates rescale logs.
//
// R6 confirmed: waves_per_eu(1,1) -> VGPR 132, E resident, 95.7 us,
// step = 449 cy of which only ~93 cy is VALU issue -> the LDS broadcast
// round-trip (issue 16 reads, drain lgkmcnt(0), THEN compute) is the chain.
//
// Hybrid broadcast, latency hidden under independent VALU:
//   j = 0..31  : v_readlane (VALU pipe, no memory latency)  - 32 rl + 32 fma
//   j = 32..63 : 8x broadcast ds_read_b128 issued FIRST; their ~120 cy
//                latency is covered by the readlane stream, then 16 pk_fma.
// (R7 compile fix: tail steps written literally — nesting STEP inside a
//  FOREACH8-expanded macro blocked the inner FOREACH8(RL4) expansion.)

constexpr int CRF_B = 1024;
constexpr int CRF_T = 512;
constexpr int CRF_K = 64;

typedef float v2f __attribute__((ext_vector_type(2)));

__device__ __forceinline__ float bcast_lane(float v, int lane) {
    return __int_as_float(__builtin_amdgcn_readlane(__float_as_int(v), lane));
}

#define FOREACH8(X)    X(0) X(1) X(2) X(3) X(4) X(5) X(6) X(7)
#define FOREACH8_HI(X) X(8) X(9) X(10) X(11) X(12) X(13) X(14) X(15)

// ---- readlane half: j = 4g..4g+3 for g = 0..7, scalar E regs ----
#define DECL_ES(g) float Es##g##_0, Es##g##_1, Es##g##_2, Es##g##_3;
#define INIT_ES(g) { const float4 t4 = trow[g];            \
    Es##g##_0 = __expf(t4.x); Es##g##_1 = __expf(t4.y);    \
    Es##g##_2 = __expf(t4.z); Es##g##_3 = __expf(t4.w); }
#define RL4(g)                                             \
    a0 = fmaf(Es##g##_0, bcast_lane(u, 4*(g)+0), a0);      \
    a1 = fmaf(Es##g##_1, bcast_lane(u, 4*(g)+1), a1);      \
    a2 = fmaf(Es##g##_2, bcast_lane(u, 4*(g)+2), a2);      \
    a3 = fmaf(Es##g##_3, bcast_lane(u, 4*(g)+3), a3);

// ---- LDS half: j = 32..63, packed E regs ----
#define DECL_EP(q) v2f Elo##q, Ehi##q;
#define INIT_EP(q) { const float4 t4 = trow[q];                    \
    Elo##q = v2f{__expf(t4.x), __expf(t4.y)};                      \
    Ehi##q = v2f{__expf(t4.z), __expf(t4.w)}; }
#define LOADW(q) const float4 w##q = src[q];
#define PKFMA(q, a, b2)                                                         \
    p##a  = __builtin_elementwise_fma(Elo##q, v2f{w##q.x, w##q.y}, p##a);       \
    p##b2 = __builtin_elementwise_fma(Ehi##q, v2f{w##q.z, w##q.w}, p##b2);

// One recurrence step: u <- (E · broadcast(u)) * Fv.
#define STEP(Fv)                                                                \
    do {                                                                        \
        wbuf[lane] = u;                          /* ds_write (broadcast src) */ \
        const float4* src = (const float4*)wbuf;                                \
        FOREACH8_HI(LOADW)                       /* 8x ds_read_b128, j>=32 */   \
        __builtin_amdgcn_sched_barrier(0);       /* reads issued before VALU */ \
        float a0 = 0.f, a1 = 0.f, a2 = 0.f, a3 = 0.f;                           \
        FOREACH8(RL4)                            /* 32 rl + 32 fma: hides DS */ \
        __builtin_amdgcn_sched_barrier(0);       /* rl block before pk block */ \
        v2f p0{0.f,0.f}, p1{0.f,0.f}, p2{0.f,0.f}, p3{0.f,0.f};                 \
        PKFMA(8,0,1)  PKFMA(9,2,3)  PKFMA(10,0,1) PKFMA(11,2,3)                 \
        PKFMA(12,0,1) PKFMA(13,2,3) PKFMA(14,0,1) PKFMA(15,2,3)                 \
        const v2f pv = (p0 + p1) + (p2 + p3);                                   \
        const float s = ((a0 + a1) + (a2 + a3)) + (pv.x + pv.y);                \
        u = s * (Fv);                                                           \
    } while (0)

__global__ __launch_bounds__(64)
__attribute__((amdgpu_waves_per_eu(1, 1)))
void crf_forward_kernel(
    const float* __restrict__ feats,      // [B, T, K]
    const float* __restrict__ trans,      // [K, K]
    const int*   __restrict__ seq_lens,   // [B]
    float*       __restrict__ out)        // [B]
{
    const int b    = blockIdx.x;
    const int lane = threadIdx.x;
    constexpr float G = 4.5f;             // per-step growth bias (baked into F)

    __shared__ __align__(16) float wbuf[CRF_K];

    const float4* trow = (const float4*)(trans + lane * CRF_K);
    FOREACH8(DECL_ES)    FOREACH8(INIT_ES)     // j = 0..31  (readlane half)
    FOREACH8_HI(DECL_EP) FOREACH8_HI(INIT_EP)  // j = 32..63 (LDS half)

    const int L   = seq_lens[b];          // uniform across the wave
    const int Lm1 = L - 1;
    const float* fb = feats + (size_t)b * CRF_T * CRF_K + lane;

    // t = 0 init (exp domain).
    const float fv0 = fb[0];
    const float m0  = bcast_lane(fv0, 0);
    float u = __expf(fv0 - m0);
    float C = m0;

    // r##q holds the raw emission for step (t + q). Prologue: steps 1..8.
#define DECL_R(q) float r##q = fb[(size_t)min(1 + q, Lm1) * CRF_K];
    FOREACH8(DECL_R)

    int t = 1;
    while (t + 8 <= L) {                  // full chunk: steps t .. t+7
#define MKF(q) const float F##q = __expf(r##q - G);
        FOREACH8(MKF)                     // factors from loads issued a chunk ago
#define RELOAD_R(q) r##q = fb[(size_t)min(t + 8 + q, Lm1) * CRF_K];
        FOREACH8(RELOAD_R)                // prefetch next chunk

        STEP(F0); STEP(F1); STEP(F2); STEP(F3);
        STEP(F4); STEP(F5); STEP(F6); STEP(F7);

        {   // once-per-chunk rescale; log is off the u-chain (feeds only C)
            const float m = bcast_lane(u, 0);
            u *= __builtin_amdgcn_rcpf(m);
            C += __logf(m);
        }
        t += 8;
    }

    // Tail: < 8 steps, factors from resident r regs. Written literally —
    // STEP contains FOREACH8, so it must not be expanded via FOREACH8.
    if (t + 0 < L) { STEP(__expf(r0 - G)); }
    if (t + 1 < L) { STEP(__expf(r1 - G)); }
    if (t + 2 < L) { STEP(__expf(r2 - G)); }
    if (t + 3 < L) { STEP(__expf(r3 - G)); }
    if (t + 4 < L) { STEP(__expf(r4 - G)); }
    if (t + 5 < L) { STEP(__expf(r5 - G)); }
    if (t + 6 < L) { STEP(__expf(r6 - G)); }
    if (t + 7 < L) { STEP(__expf(r7 - G)); }

    C += G * (float)Lm1;                  // restore the baked bias

    // Final LSE over lanes: out = C + log(sum_i u[i]).
    float e = u;
#pragma unroll
    for (int off = 32; off > 0; off >>= 1) e += __shfl_xor(e, off, 64);
    if (lane == 0) out[b] = C + __logf(e);
}

extern "C" void kernel_launch(void* const* d_in, const int* in_sizes, int n_in,
                              void* d_out, int out_size, void* d_ws, size_t ws_size,
                              hipStream_t stream)
{
    const float* feats    = (const float*)d_in[0];
    const float* trans    = (const float*)d_in[1];
    const int*   seq_lens = (const int*)d_in[2];
    float*       out      = (float*)d_out;

    crf_forward_kernel<<<dim3(CRF_B), dim3(CRF_K), 0, stream>>>(
        feats, trans, seq_lens, out);
}